// Round 1
// 1886.660 us; speedup vs baseline: 1.0155x; 1.0155x over previous
//
#include <hip/hip_runtime.h>
#include <math.h>

#define K_N   30
#define D_DIM 64

typedef float f4 __attribute__((ext_vector_type(4)));

// One 64-lane wave per row b. 4 waves / 256-thread block.
//  - lanes 0..29: per-neighbor similarity + logits + softmax weights
//  - all 64 lanes: coalesced float4 streaming of the 30x64 context row
// ctx/sd/out are single-use streams -> non-temporal (nt) to avoid L2/L3
// allocation; kern/bias are the only reused data and stay cached.
__global__ __launch_bounds__(256) void attn_fused_kernel(
    const float* __restrict__ sd,    // [B, K]
    const float* __restrict__ ctx,   // [B, K, D]
    const float* __restrict__ kern,  // [K, K]
    const float* __restrict__ bias,  // [K]
    float* __restrict__ out,         // [B, D]
    int B)
{
    const int lane = threadIdx.x & 63;
    const int wave = threadIdx.x >> 6;
    const long long b = (long long)blockIdx.x * 4 + wave;
    if (b >= B) return;

    // ---- Issue the context-row loads early: 30*64 floats = 480 float4.
    // 8 iters x 64 lanes x float4; iter 7 is half-masked (f >= 480).
    const f4* __restrict__ crow =
        (const f4*)(ctx + b * (long long)(K_N * D_DIM));
    f4 v[8];
#pragma unroll
    for (int t = 0; t < 8; ++t) {
        const int f = t * 64 + lane;
        if (f < (K_N * D_DIM / 4)) {
            v[t] = __builtin_nontemporal_load(crow + f);
        } else {
            v[t] = (f4){0.f, 0.f, 0.f, 0.f};
        }
    }

    // ---- simi[k] = exp(-d^2 / 2), held in lane k ----
    float simi = 0.f;
    if (lane < K_N) {
        const float d = __builtin_nontemporal_load(sd + b * (long long)K_N + lane);
        simi = __expf(-0.5f * d * d);
    }

    // ---- logits[j] = bias[j] + sum_k simi[k] * kern[k][j], lane j holds logit[j]
    float logit = (lane < K_N) ? bias[lane] : -INFINITY;
#pragma unroll
    for (int k = 0; k < K_N; ++k) {
        const float kv = (lane < K_N) ? kern[k * K_N + lane] : 0.f;
        const float s  = __shfl(simi, k, 64);   // wave-uniform broadcast
        logit = fmaf(s, kv, logit);             // -inf lanes stay -inf
    }

    // ---- softmax over lanes 0..29 (lanes >=30 contribute -inf / 0) ----
    float m = logit;
#pragma unroll
    for (int off = 32; off; off >>= 1) m = fmaxf(m, __shfl_xor(m, off, 64));
    const float e = (lane < K_N) ? __expf(logit - m) : 0.f;
    float ssum = e;
#pragma unroll
    for (int off = 32; off; off >>= 1) ssum += __shfl_xor(ssum, off, 64);
    const float w = e / ssum;   // lane k holds weight[k] (0 for k >= K_N)

    // ---- weighted aggregation: each float4 f covers k = f>>4, d = 4*(f&15)..+3
    f4 acc = {0.f, 0.f, 0.f, 0.f};
#pragma unroll
    for (int t = 0; t < 8; ++t) {
        const int f = t * 64 + lane;
        int k = f >> 4;
        if (k > K_N - 1) k = K_N - 1;          // masked lanes have v=0 anyway
        const float wk = __shfl(w, k, 64);     // per-lane bpermute
        acc.x = fmaf(wk, v[t].x, acc.x);
        acc.y = fmaf(wk, v[t].y, acc.y);
        acc.z = fmaf(wk, v[t].z, acc.z);
        acc.w = fmaf(wk, v[t].w, acc.w);
    }

    // lanes {i, i+16, i+32, i+48} share the same d-range -> xor-16/32 reduce
#pragma unroll
    for (int off = 16; off <= 32; off <<= 1) {
        acc.x += __shfl_xor(acc.x, off, 64);
        acc.y += __shfl_xor(acc.y, off, 64);
        acc.z += __shfl_xor(acc.z, off, 64);
        acc.w += __shfl_xor(acc.w, off, 64);
    }

    if (lane < 16) {
        __builtin_nontemporal_store(
            acc, (f4*)(out + b * (long long)D_DIM) + lane);
    }
}

extern "C" void kernel_launch(void* const* d_in, const int* in_sizes, int n_in,
                              void* d_out, int out_size, void* d_ws, size_t ws_size,
                              hipStream_t stream) {
    const float* sd   = (const float*)d_in[0];  // [B, K]
    const float* ctx  = (const float*)d_in[1];  // [B, K, D]
    const float* kern = (const float*)d_in[2];  // [K, K]
    const float* bias = (const float*)d_in[3];  // [K]
    float* out = (float*)d_out;                 // [B, D]

    const int B = in_sizes[0] / K_N;            // 200000
    const int blocks = (B + 3) / 4;             // 4 rows (waves) per block

    hipLaunchKernelGGL(attn_fused_kernel, dim3(blocks), dim3(256), 0, stream,
                       sd, ctx, kern, bias, out, B);
}